// Round 17
// baseline (146.771 us; speedup 1.0000x reference)
//
#include <hip/hip_runtime.h>

// B=2, S=4096, D=512, H=8, DH=64
// ws (f16): [enc16|ml] 8MB | Q 8MB | K 8MB | Vp 8MB | Wt x4 2MB | att 8MB; pO in d_out.
// All MFMA: 32x32x16 f16. C/D map (m74/m101): col=l&31, row=(r&3)+8*(r>>2)+4*(l>>5).

typedef _Float16 f16x8 __attribute__((ext_vector_type(8)));
typedef float f32x16 __attribute__((ext_vector_type(16)));

__device__ __forceinline__ f32x16 mma32(f16x8 a, f16x8 b, f32x16 c) {
  return __builtin_amdgcn_mfma_f32_32x32x16_f16(a, b, c, 0, 0, 0);
}

__device__ __forceinline__ void gload16(const void* g, void* l) {
  __builtin_amdgcn_global_load_lds((const __attribute__((address_space(1))) void*)g,
                                   (__attribute__((address_space(3))) void*)l, 16, 0, 0);
}

// ---- prep: enc f32->f16 (blocks 0..2047) + 4x W transpose->f16 (blocks 2048..3071)
__global__ __launch_bounds__(256) void prep_k(const float* __restrict__ enc,
                                              const float* __restrict__ WQ,
                                              const float* __restrict__ WK,
                                              const float* __restrict__ WV,
                                              const float* __restrict__ WO,
                                              _Float16* __restrict__ enc16,
                                              _Float16* __restrict__ WtQ,
                                              _Float16* __restrict__ WtK,
                                              _Float16* __restrict__ WtV,
                                              _Float16* __restrict__ WtO) {
  const int bid = blockIdx.x;
  if (bid < 2048) {
    const size_t i = (size_t)bid * 256 + threadIdx.x;  // 8 elems each
    const float4* p = (const float4*)(enc + i * 8);
    const float4 a = p[0], b = p[1];
    union { f16x8 v; uint4 u; } r;
    r.v[0] = (_Float16)a.x; r.v[1] = (_Float16)a.y; r.v[2] = (_Float16)a.z; r.v[3] = (_Float16)a.w;
    r.v[4] = (_Float16)b.x; r.v[5] = (_Float16)b.y; r.v[6] = (_Float16)b.z; r.v[7] = (_Float16)b.w;
    *(uint4*)(enc16 + i * 8) = r.u;
  } else {
    const int t = bid - 2048;
    const int wsel = t >> 8;
    const float* W = (wsel == 0) ? WQ : (wsel == 1) ? WK : (wsel == 2) ? WV : WO;
    _Float16* T = (wsel == 0) ? WtQ : (wsel == 1) ? WtK : (wsel == 2) ? WtV : WtO;
    const int tb = t & 255;
    const int k0 = (tb & 15) * 32, n0 = (tb >> 4) * 32;
    __shared__ float tt[32][33];
    const int c = threadIdx.x & 31, r8 = threadIdx.x >> 5;
#pragma unroll
    for (int p = 0; p < 4; ++p) tt[c][r8 + 8 * p] = W[(size_t)(k0 + r8 + 8 * p) * 512 + n0 + c];
    __syncthreads();
#pragma unroll
    for (int p = 0; p < 4; ++p)
      T[(size_t)(n0 + r8 + 8 * p) * 512 + k0 + c] = (_Float16)tt[r8 + 8 * p][c];
  }
}

// ---- shared GEMM core: C128x128, BK=64, 4 waves (2x2), dbuf LDS via global_load_lds
__device__ __forceinline__ void gemm_core(const _Float16* __restrict__ A,
                                          const _Float16* __restrict__ Wt,
                                          int m0, int n0,
                                          _Float16* Al, _Float16* Bl,
                                          f32x16 acc[2][2]) {
  const int tid = threadIdx.x, w = tid >> 6, l = tid & 63;
  const int hi = l >> 5, li = l & 31;
  const int wm = w >> 1, wn = w & 1;
  const int srow = l >> 3, sunit = (l & 7) ^ (l >> 3);
  const int arow = 32 * w;

#pragma unroll
  for (int mb = 0; mb < 2; ++mb)
#pragma unroll
    for (int nb = 0; nb < 2; ++nb)
#pragma unroll
      for (int r = 0; r < 16; ++r) acc[mb][nb][r] = 0.f;

#pragma unroll
  for (int i = 0; i < 4; ++i) {  // prologue: k-step 0 -> buf 0
    gload16(A + (size_t)(m0 + arow + 8 * i + srow) * 512 + sunit * 8, Al + (arow + 8 * i) * 64);
    gload16(Wt + (size_t)(n0 + arow + 8 * i + srow) * 512 + sunit * 8, Bl + (arow + 8 * i) * 64);
  }
  for (int kk = 0; kk < 8; ++kk) {
    const int cur = kk & 1;
    __syncthreads();
    if (kk < 7) {
      const int kn = (kk + 1) * 64;
#pragma unroll
      for (int i = 0; i < 4; ++i) {
        gload16(A + (size_t)(m0 + arow + 8 * i + srow) * 512 + kn + sunit * 8,
                Al + (cur ^ 1) * 8192 + (arow + 8 * i) * 64);
        gload16(Wt + (size_t)(n0 + arow + 8 * i + srow) * 512 + kn + sunit * 8,
                Bl + (cur ^ 1) * 8192 + (arow + 8 * i) * 64);
      }
    }
#pragma unroll
    for (int ks = 0; ks < 4; ++ks) {
      f16x8 af[2], bf[2];
#pragma unroll
      for (int mb = 0; mb < 2; ++mb)
        af[mb] = *(const f16x8*)((const char*)(Al + cur * 8192 + (64 * wm + 32 * mb + li) * 64) +
                                 (((2 * ks + hi) ^ (li & 7)) << 4));
#pragma unroll
      for (int nb = 0; nb < 2; ++nb)
        bf[nb] = *(const f16x8*)((const char*)(Bl + cur * 8192 + (64 * wn + 32 * nb + li) * 64) +
                                 (((2 * ks + hi) ^ (li & 7)) << 4));
#pragma unroll
      for (int mb = 0; mb < 2; ++mb)
#pragma unroll
        for (int nb = 0; nb < 2; ++nb) acc[mb][nb] = mma32(af[mb], bf[nb], acc[mb][nb]);
    }
  }
}

// ---- fused QKV projection: grid (64, 12); y>>2 selects W; y&3 selects n0
__global__ __launch_bounds__(256) void qkv_k(const _Float16* __restrict__ A,
                                             const _Float16* __restrict__ WtQ,
                                             const _Float16* __restrict__ WtK,
                                             const _Float16* __restrict__ WtV,
                                             _Float16* __restrict__ Qw,
                                             _Float16* __restrict__ Kw,
                                             _Float16* __restrict__ Vpw,
                                             float qscale) {
  __shared__ __align__(16) _Float16 Al[2 * 128 * 64];
  __shared__ __align__(16) _Float16 Bl[2 * 128 * 64];
  const int m0 = blockIdx.x * 128;
  const int wid = blockIdx.y >> 2, n0 = (blockIdx.y & 3) * 128;
  const _Float16* Wt = (wid == 0) ? WtQ : (wid == 1) ? WtK : WtV;
  f32x16 acc[2][2];
  gemm_core(A, Wt, m0, n0, Al, Bl, acc);

  const int tid = threadIdx.x, w = tid >> 6, l = tid & 63;
  const int hi = l >> 5, li = l & 31;
  const int wm = w >> 1, wn = w & 1;
  if (wid < 2) {
    _Float16* Cp = (wid == 0) ? Qw : Kw;
    const float scale = (wid == 0) ? qscale : 1.f;
#pragma unroll
    for (int mb = 0; mb < 2; ++mb)
#pragma unroll
      for (int nb = 0; nb < 2; ++nb)
#pragma unroll
        for (int r = 0; r < 16; ++r) {
          const int m = m0 + 64 * wm + 32 * mb + (r & 3) + 8 * (r >> 2) + 4 * hi;
          const int n = n0 + 64 * wn + 32 * nb + li;
          const int b = m >> 12, s = m & 4095, h = n >> 6, d = n & 63;
          Cp[((((size_t)b * 8 + h) * 4096 + s) << 6) + d] = (_Float16)(acc[mb][nb][r] * scale);
        }
  } else {
    // Vp: [b,h][d][s-perm]; within each s-16-block, pos p holds s = (p&3)+8((p>>2)&1)+4(p>>3)
#pragma unroll
    for (int mb = 0; mb < 2; ++mb)
#pragma unroll
      for (int nb = 0; nb < 2; ++nb)
#pragma unroll
        for (int c = 0; c < 4; ++c) {
          const int mbase = m0 + 64 * wm + 32 * mb + 16 * (c >> 1);
          const int n = n0 + 64 * wn + 32 * nb + li;
          const int b = mbase >> 12, sb = mbase & 4095, h = n >> 6, d = n & 63;
          union { uint2 u; _Float16 h4[4]; } t4;
#pragma unroll
          for (int t = 0; t < 4; ++t) t4.h4[t] = (_Float16)acc[mb][nb][4 * c + t];
          *(uint2*)(Vpw + ((((size_t)b * 8 + h) * 64 + d) << 12) + sb + 4 * (c & 1) + 8 * hi) = t4.u;
        }
  }
}

// ---- final projection: att(f16) @ WtO -> out f32
__global__ __launch_bounds__(256) void fgemm_k(const _Float16* __restrict__ A,
                                               const _Float16* __restrict__ Wt,
                                               float* __restrict__ out) {
  __shared__ __align__(16) _Float16 Al[2 * 128 * 64];
  __shared__ __align__(16) _Float16 Bl[2 * 128 * 64];
  const int m0 = blockIdx.x * 128, n0 = blockIdx.y * 128;
  f32x16 acc[2][2];
  gemm_core(A, Wt, m0, n0, Al, Bl, acc);
  const int tid = threadIdx.x, w = tid >> 6, l = tid & 63;
  const int hi = l >> 5, li = l & 31;
  const int wm = w >> 1, wn = w & 1;
#pragma unroll
  for (int mb = 0; mb < 2; ++mb)
#pragma unroll
    for (int nb = 0; nb < 2; ++nb)
#pragma unroll
      for (int r = 0; r < 16; ++r) {
        const int m = m0 + 64 * wm + 32 * mb + (r & 3) + 8 * (r >> 2) + 4 * hi;
        const int n = n0 + 64 * wn + 32 * nb + li;
        out[(size_t)m * 512 + n] = acc[mb][nb][r];
      }
}

// ---- flash v17: 4 waves x 32q = 128-row Q tile + ONE barrier period per 128-k
// pair (K[128][64]+V[64][128], 32KB sbuf). Split-KV uniform 20-tile chunks (r11).
__global__ __launch_bounds__(256) void flash_k(const _Float16* __restrict__ Q,
                                               const _Float16* __restrict__ K,
                                               const _Float16* __restrict__ Vp,
                                               _Float16* __restrict__ att,
                                               _Float16* __restrict__ pO,
                                               float2* __restrict__ ml) {
  __shared__ __align__(16) _Float16 Kl[128 * 64];  // [k-row 128][d 64]
  __shared__ __align__(16) _Float16 Vl[64 * 128];  // [d 64][s 128]

  const int u = blockIdx.x;  // 1088 blocks
  const int bh = u & 15;
  const int j = 67 - (u >> 4);  // 0..67, longest chunks dispatched first
  int qt, cc;                   // qt: 128-row Q-tile index (0..31)
  if (j < 10) { qt = j; cc = 0; }
  else if (j < 30) { qt = 10 + ((j - 10) >> 1); cc = (j - 10) & 1; }
  else if (j < 60) { qt = 20 + (j - 30) / 3; cc = (j - 30) % 3; }
  else { qt = 30 + ((j - 60) >> 2); cc = (j - 60) & 3; }
  const int nt = 2 * qt + 2;      // 64-k tiles for this Q-tile
  const int ktlo = 20 * cc;       // even
  const int kthi = min(ktlo + 19, nt - 1);  // always odd (nt even)
  const bool split = (nt > 20);
  const int q0 = qt * 128;
  const int tid = threadIdx.x, w = tid >> 6, l = tid & 63;
  const int hi = l >> 5, li = l & 31;

  const size_t bhoff = (size_t)bh * 4096 * 64;
  const _Float16* Kb = K + bhoff;
  const _Float16* Vb = Vp + bhoff;  // [d][s-perm]
  const _Float16* Qb = Q + bhoff;   // [s][d], pre-scaled by 0.125*log2e
  const int qg = q0 + 32 * w + li;

  f16x8 qB[4];
#pragma unroll
  for (int ks = 0; ks < 4; ++ks)
    qB[ks] = *(const f16x8*)(Qb + (size_t)qg * 64 + 16 * ks + 8 * hi);

  f32x16 o2[2], lacc;
#pragma unroll
  for (int db = 0; db < 2; ++db)
#pragma unroll
    for (int r = 0; r < 16; ++r) o2[db][r] = 0.f;
#pragma unroll
  for (int r = 0; r < 16; ++r) lacc[r] = 0.f;
  float m_ = -__builtin_inff();

  auto tile_step = [&](int kt, int half) {
    f32x16 s2[2];
#pragma unroll
    for (int kb = 0; kb < 2; ++kb)
#pragma unroll
      for (int r = 0; r < 16; ++r) s2[kb][r] = 0.f;
    __builtin_amdgcn_s_setprio(1);
#pragma unroll
    for (int ks = 0; ks < 4; ++ks)
#pragma unroll
      for (int kb = 0; kb < 2; ++kb) {
        const f16x8 kf = *(const f16x8*)(
            (const char*)(Kl + (64 * half + 32 * kb + li) * 64) +
            (((2 * ks + hi) ^ (li & 7)) << 4));
        s2[kb] = mma32(kf, qB[ks], s2[kb]);
      }
    __builtin_amdgcn_s_setprio(0);

    if (kt >= 2 * qt) {  // tiles crossing the 128-row Q block's diagonal
      const int limit = qg - kt * 64;
#pragma unroll
      for (int kb = 0; kb < 2; ++kb)
#pragma unroll
        for (int r = 0; r < 16; ++r) {
          const int kl = 32 * kb + (r & 3) + 8 * (r >> 2) + 4 * hi;
          if (kl > limit) s2[kb][r] = -__builtin_inff();
        }
    }

#define RV(i) s2[(i) >> 4][(i) & 15]
    float a[11];
#pragma unroll
    for (int i = 0; i < 10; ++i)
      a[i] = fmaxf(fmaxf(RV(3 * i), RV(3 * i + 1)), RV(3 * i + 2));
    a[10] = fmaxf(RV(30), RV(31));
#undef RV
    float b4[4];
    b4[0] = fmaxf(fmaxf(a[0], a[1]), a[2]);
    b4[1] = fmaxf(fmaxf(a[3], a[4]), a[5]);
    b4[2] = fmaxf(fmaxf(a[6], a[7]), a[8]);
    b4[3] = fmaxf(a[9], a[10]);
    const float mxl = fmaxf(fmaxf(fmaxf(b4[0], b4[1]), b4[2]), b4[3]);

    if (!__all(mxl <= m_ + 8.f)) {  // defer-max
      const float vm = fmaxf(mxl, __shfl_xor(mxl, 32, 64));
      const float mn = fmaxf(m_, vm);
      const float al = __builtin_amdgcn_exp2f(m_ - mn);
      m_ = mn;
#pragma unroll
      for (int r = 0; r < 16; ++r) lacc[r] *= al;
#pragma unroll
      for (int db = 0; db < 2; ++db)
#pragma unroll
        for (int r = 0; r < 16; ++r) o2[db][r] *= al;
    }
#pragma unroll
    for (int kb = 0; kb < 2; ++kb)
#pragma unroll
      for (int r = 0; r < 16; ++r) s2[kb][r] = __builtin_amdgcn_exp2f(s2[kb][r] - m_);
#pragma unroll
    for (int kb = 0; kb < 2; ++kb)
#pragma unroll
      for (int r = 0; r < 16; ++r) lacc[r] += s2[kb][r];

    f16x8 pb[4];
#pragma unroll
    for (int ks = 0; ks < 4; ++ks) {
      union { f16x8 v; unsigned int u[4]; } pu;
      const int kb = ks >> 1, base = 8 * (ks & 1);
#pragma unroll
      for (int p2 = 0; p2 < 4; ++p2)
        pu.u[p2] = __builtin_bit_cast(unsigned int,
                     __builtin_amdgcn_cvt_pkrtz(s2[kb][base + 2 * p2], s2[kb][base + 2 * p2 + 1]));
      pb[ks] = pu.v;
    }

    __builtin_amdgcn_s_setprio(1);
#pragma unroll
    for (int ks = 0; ks < 4; ++ks)
#pragma unroll
      for (int db = 0; db < 2; ++db) {
        const f16x8 vf = *(const f16x8*)(
            (const char*)(Vl + (32 * db + li) * 128) +
            ((((8 * half + 2 * ks + hi)) ^ (li & 15)) << 4));
        o2[db] = mma32(vf, pb[ks], o2[db]);
      }
    __builtin_amdgcn_s_setprio(0);
  };

  const int npair = (kthi - ktlo + 1) >> 1;  // kthi odd, ktlo even -> exact pairs
  for (int p = 0; p < npair; ++p) {
    const int kt0 = ktlo + 2 * p;
    const int k0 = kt0 * 64;
    if (p) __syncthreads();  // all reads of Kl/Vl done before overwrite
    // stage K pair (128 rows): wave w does rows [32w, 32w+32)
#pragma unroll
    for (int e = 0; e < 4; ++e) {
      const int kr = 32 * w + 8 * e;
      gload16(Kb + (size_t)(k0 + kr + (l >> 3)) * 64 + (((l & 7) ^ ((l >> 3) & 7)) << 3),
              Kl + kr * 64);
    }
    // stage V pair (64 d-rows x 128 s): wave w does rows [16w, 16w+16)
#pragma unroll
    for (int e = 0; e < 4; ++e) {
      const int vr = 16 * w + 4 * e;
      gload16(Vb + (size_t)(vr + (l >> 4)) * 4096 + k0 +
                  ((((l & 15) ^ ((4 * e + (l >> 4)) & 15))) << 3),
              Vl + vr * 128);
    }
    __syncthreads();  // vmcnt drain + visibility

    tile_step(kt0, 0);
    tile_step(kt0 + 1, 1);
  }

  // epilogue
  float t8[8];
#pragma unroll
  for (int i = 0; i < 8; ++i) t8[i] = lacc[i] + lacc[i + 8];
  float lsum = ((t8[0] + t8[1]) + (t8[2] + t8[3])) + ((t8[4] + t8[5]) + (t8[6] + t8[7]));
  lsum += __shfl_xor(lsum, 32, 64);
  const float inv = 1.f / lsum;
  if (!split) {
    const int b = bh >> 3, h = bh & 7;
    _Float16* op = att + ((size_t)b * 4096 + qg) * 512 + h * 64;
#pragma unroll
    for (int db = 0; db < 2; ++db)
#pragma unroll
      for (int c = 0; c < 4; ++c) {
        union { uint2 u; _Float16 h4[4]; } t4;
#pragma unroll
        for (int t = 0; t < 4; ++t) t4.h4[t] = (_Float16)(o2[db][4 * c + t] * inv);
        *(uint2*)(op + 32 * db + 8 * c + 4 * hi) = t4.u;
      }
  } else {
    // compact slot: per bh, qt 10..19 -> 2 slots, 20..29 -> 3, 30..31 -> 4 (58 total)
    int off;
    if (qt < 20) off = (qt - 10) * 2;
    else if (qt < 30) off = 20 + (qt - 20) * 3;
    else off = 50 + (qt - 30) * 4;
    const int slot = bh * 58 + off + cc;
    const int qrow = 32 * w + li;  // 0..127
    _Float16* op = pO + (size_t)slot * 8192 + qrow * 64;
#pragma unroll
    for (int db = 0; db < 2; ++db)
#pragma unroll
      for (int c = 0; c < 4; ++c) {
        union { uint2 u; _Float16 h4[4]; } t4;
#pragma unroll
        for (int t = 0; t < 4; ++t) t4.h4[t] = (_Float16)(o2[db][4 * c + t] * inv);
        *(uint2*)(op + 32 * db + 8 * c + 4 * hi) = t4.u;
      }
    if (hi == 0) ml[slot * 128 + qrow] = make_float2(m_, lsum);
  }
}

// ---- combine: merge nc (2..4) normalized partials per (bh, qt>=10, qrow) -> att
__global__ __launch_bounds__(256) void combine_k(const float2* __restrict__ ml,
                                                 const _Float16* __restrict__ pO,
                                                 _Float16* __restrict__ att) {
  const int tid = threadIdx.x;
  const int rid = blockIdx.x * 8 + (tid >> 5);  // 45056 rows (16 bh x 22 qt x 128)
  const int d2 = tid & 31;
  const int bh = rid / 2816, rem = rid % 2816;
  const int qt = 10 + (rem >> 7), qrow = rem & 127;
  const int nc = (qt < 20) ? 2 : (qt < 30) ? 3 : 4;
  int off;
  if (qt < 20) off = (qt - 10) * 2;
  else if (qt < 30) off = 20 + (qt - 20) * 3;
  else off = 50 + (qt - 30) * 4;
  const int slot0 = bh * 58 + off;

  float2 mlc[4];
  float M = -__builtin_inff();
#pragma unroll
  for (int c = 0; c < 4; ++c)
    if (c < nc) {
      mlc[c] = ml[(slot0 + c) * 128 + qrow];
      M = fmaxf(M, mlc[c].x);
    }
  float wc[4], wsum = 0.f;
#pragma unroll
  for (int c = 0; c < 4; ++c)
    if (c < nc) {
      wc[c] = __builtin_amdgcn_exp2f(mlc[c].x - M) * mlc[c].y;
      wsum += wc[c];
    }
  const float inv = 1.f / wsum;
  float acc0 = 0.f, acc1 = 0.f;
#pragma unroll
  for (int c = 0; c < 4; ++c)
    if (c < nc) {
      union { unsigned int u; _Float16 h2[2]; } x;
      x.u = *(const unsigned int*)(pO + (size_t)(slot0 + c) * 8192 + qrow * 64 + 2 * d2);
      const float a = wc[c] * inv;
      acc0 += (float)x.h2[0] * a;
      acc1 += (float)x.h2[1] * a;
    }
  union { unsigned int u; _Float16 h2[2]; } y;
  y.h2[0] = (_Float16)acc0;
  y.h2[1] = (_Float16)acc1;
  const int b = bh >> 3, h = bh & 7, q = qt * 128 + qrow;
  *(unsigned int*)(att + ((size_t)b * 4096 + q) * 512 + h * 64 + 2 * d2) = y.u;
}

extern "C" void kernel_launch(void* const* d_in, const int* in_sizes, int n_in,
                              void* d_out, int out_size, void* d_ws, size_t ws_size,
                              hipStream_t stream) {
  const float* enc = (const float*)d_in[0];
  const float* WQ = (const float*)d_in[2];
  const float* WK = (const float*)d_in[3];
  const float* WV = (const float*)d_in[4];
  const float* WO = (const float*)d_in[5];
  float* out = (float*)d_out;

  const size_t NE = (size_t)2 * 8 * 4096 * 64;  // 4,194,304
  _Float16* enc16 = (_Float16*)d_ws;            // 8MB; aliased with ml (enc16 dead after qkv)
  _Float16* Qw = enc16 + NE;
  _Float16* Kw = Qw + NE;
  _Float16* Vpw = Kw + NE;
  _Float16* WtQ = Vpw + NE;
  _Float16* WtK = WtQ + 512 * 512;
  _Float16* WtV = WtK + 512 * 512;
  _Float16* WtO = WtV + 512 * 512;
  _Float16* att = WtO + 512 * 512;              // 8MB
  float2* ml = (float2*)enc16;                  // 950KB, aliases dead enc16
  _Float16* pO = (_Float16*)d_out;              // 14.5MB scratch in d_out (fgemm overwrites)

  prep_k<<<3072, 256, 0, stream>>>(enc, WQ, WK, WV, WO, enc16, WtQ, WtK, WtV, WtO);
  // 0.125 (1/sqrt(64)) * log2(e) folded into Q
  qkv_k<<<dim3(64, 12), 256, 0, stream>>>(enc16, WtQ, WtK, WtV, Qw, Kw, Vpw, 0.1803368801f);
  flash_k<<<1088, 256, 0, stream>>>(Qw, Kw, Vpw, att, pO, ml);
  combine_k<<<5632, 256, 0, stream>>>(ml, pO, att);
  fgemm_k<<<dim3(64, 4), 256, 0, stream>>>(att, WtO, out);
}

// Round 18
// 111.294 us; speedup vs baseline: 1.3188x; 1.3188x over previous
//
#include <hip/hip_runtime.h>

// B=2, S=4096, D=512, H=8, DH=64
// ws (f16): [enc16 | partialO] 8MB | Q 8MB | K 8MB | Vp 8MB | [WtQ|ml 0.5MB] WtK WtV WtO | att 8MB
// All MFMA: 32x32x16 f16. C/D map (m74/m101): col=l&31, row=(r&3)+8*(r>>2)+4*(l>>5).

typedef _Float16 f16x8 __attribute__((ext_vector_type(8)));
typedef float f32x16 __attribute__((ext_vector_type(16)));

__device__ __forceinline__ f32x16 mma32(f16x8 a, f16x8 b, f32x16 c) {
  return __builtin_amdgcn_mfma_f32_32x32x16_f16(a, b, c, 0, 0, 0);
}

__device__ __forceinline__ void gload16(const void* g, void* l) {
  __builtin_amdgcn_global_load_lds((const __attribute__((address_space(1))) void*)g,
                                   (__attribute__((address_space(3))) void*)l, 16, 0, 0);
}

// ---- prep: enc f32->f16 (blocks 0..2047) + 4x W transpose->f16 (blocks 2048..3071)
__global__ __launch_bounds__(256) void prep_k(const float* __restrict__ enc,
                                              const float* __restrict__ WQ,
                                              const float* __restrict__ WK,
                                              const float* __restrict__ WV,
                                              const float* __restrict__ WO,
                                              _Float16* __restrict__ enc16,
                                              _Float16* __restrict__ WtQ,
                                              _Float16* __restrict__ WtK,
                                              _Float16* __restrict__ WtV,
                                              _Float16* __restrict__ WtO) {
  const int bid = blockIdx.x;
  if (bid < 2048) {
    const size_t i = (size_t)bid * 256 + threadIdx.x;  // 8 elems each
    const float4* p = (const float4*)(enc + i * 8);
    const float4 a = p[0], b = p[1];
    union { f16x8 v; uint4 u; } r;
    r.v[0] = (_Float16)a.x; r.v[1] = (_Float16)a.y; r.v[2] = (_Float16)a.z; r.v[3] = (_Float16)a.w;
    r.v[4] = (_Float16)b.x; r.v[5] = (_Float16)b.y; r.v[6] = (_Float16)b.z; r.v[7] = (_Float16)b.w;
    *(uint4*)(enc16 + i * 8) = r.u;
  } else {
    const int t = bid - 2048;
    const int wsel = t >> 8;
    const float* W = (wsel == 0) ? WQ : (wsel == 1) ? WK : (wsel == 2) ? WV : WO;
    _Float16* T = (wsel == 0) ? WtQ : (wsel == 1) ? WtK : (wsel == 2) ? WtV : WtO;
    const int tb = t & 255;
    const int k0 = (tb & 15) * 32, n0 = (tb >> 4) * 32;
    __shared__ float tt[32][33];
    const int c = threadIdx.x & 31, r8 = threadIdx.x >> 5;
#pragma unroll
    for (int p = 0; p < 4; ++p) tt[c][r8 + 8 * p] = W[(size_t)(k0 + r8 + 8 * p) * 512 + n0 + c];
    __syncthreads();
#pragma unroll
    for (int p = 0; p < 4; ++p)
      T[(size_t)(n0 + r8 + 8 * p) * 512 + k0 + c] = (_Float16)tt[r8 + 8 * p][c];
  }
}

// ---- shared GEMM core: C128x128, BK=64, 4 waves (2x2), dbuf LDS via global_load_lds
__device__ __forceinline__ void gemm_core(const _Float16* __restrict__ A,
                                          const _Float16* __restrict__ Wt,
                                          int m0, int n0,
                                          _Float16* Al, _Float16* Bl,
                                          f32x16 acc[2][2]) {
  const int tid = threadIdx.x, w = tid >> 6, l = tid & 63;
  const int hi = l >> 5, li = l & 31;
  const int wm = w >> 1, wn = w & 1;
  const int srow = l >> 3, sunit = (l & 7) ^ (l >> 3);
  const int arow = 32 * w;

#pragma unroll
  for (int mb = 0; mb < 2; ++mb)
#pragma unroll
    for (int nb = 0; nb < 2; ++nb)
#pragma unroll
      for (int r = 0; r < 16; ++r) acc[mb][nb][r] = 0.f;

#pragma unroll
  for (int i = 0; i < 4; ++i) {  // prologue: k-step 0 -> buf 0
    gload16(A + (size_t)(m0 + arow + 8 * i + srow) * 512 + sunit * 8, Al + (arow + 8 * i) * 64);
    gload16(Wt + (size_t)(n0 + arow + 8 * i + srow) * 512 + sunit * 8, Bl + (arow + 8 * i) * 64);
  }
  for (int kk = 0; kk < 8; ++kk) {
    const int cur = kk & 1;
    __syncthreads();
    if (kk < 7) {
      const int kn = (kk + 1) * 64;
#pragma unroll
      for (int i = 0; i < 4; ++i) {
        gload16(A + (size_t)(m0 + arow + 8 * i + srow) * 512 + kn + sunit * 8,
                Al + (cur ^ 1) * 8192 + (arow + 8 * i) * 64);
        gload16(Wt + (size_t)(n0 + arow + 8 * i + srow) * 512 + kn + sunit * 8,
                Bl + (cur ^ 1) * 8192 + (arow + 8 * i) * 64);
      }
    }
#pragma unroll
    for (int ks = 0; ks < 4; ++ks) {
      f16x8 af[2], bf[2];
#pragma unroll
      for (int mb = 0; mb < 2; ++mb)
        af[mb] = *(const f16x8*)((const char*)(Al + cur * 8192 + (64 * wm + 32 * mb + li) * 64) +
                                 (((2 * ks + hi) ^ (li & 7)) << 4));
#pragma unroll
      for (int nb = 0; nb < 2; ++nb)
        bf[nb] = *(const f16x8*)((const char*)(Bl + cur * 8192 + (64 * wn + 32 * nb + li) * 64) +
                                 (((2 * ks + hi) ^ (li & 7)) << 4));
#pragma unroll
      for (int mb = 0; mb < 2; ++mb)
#pragma unroll
        for (int nb = 0; nb < 2; ++nb) acc[mb][nb] = mma32(af[mb], bf[nb], acc[mb][nb]);
    }
  }
}

// ---- fused QKV projection: grid (64, 12); y>>2 selects W; y&3 selects n0
__global__ __launch_bounds__(256) void qkv_k(const _Float16* __restrict__ A,
                                             const _Float16* __restrict__ WtQ,
                                             const _Float16* __restrict__ WtK,
                                             const _Float16* __restrict__ WtV,
                                             _Float16* __restrict__ Qw,
                                             _Float16* __restrict__ Kw,
                                             _Float16* __restrict__ Vpw,
                                             float qscale) {
  __shared__ __align__(16) _Float16 Al[2 * 128 * 64];
  __shared__ __align__(16) _Float16 Bl[2 * 128 * 64];
  const int m0 = blockIdx.x * 128;
  const int wid = blockIdx.y >> 2, n0 = (blockIdx.y & 3) * 128;
  const _Float16* Wt = (wid == 0) ? WtQ : (wid == 1) ? WtK : WtV;
  f32x16 acc[2][2];
  gemm_core(A, Wt, m0, n0, Al, Bl, acc);

  const int tid = threadIdx.x, w = tid >> 6, l = tid & 63;
  const int hi = l >> 5, li = l & 31;
  const int wm = w >> 1, wn = w & 1;
  if (wid < 2) {
    _Float16* Cp = (wid == 0) ? Qw : Kw;
    const float scale = (wid == 0) ? qscale : 1.f;
#pragma unroll
    for (int mb = 0; mb < 2; ++mb)
#pragma unroll
      for (int nb = 0; nb < 2; ++nb)
#pragma unroll
        for (int r = 0; r < 16; ++r) {
          const int m = m0 + 64 * wm + 32 * mb + (r & 3) + 8 * (r >> 2) + 4 * hi;
          const int n = n0 + 64 * wn + 32 * nb + li;
          const int b = m >> 12, s = m & 4095, h = n >> 6, d = n & 63;
          Cp[((((size_t)b * 8 + h) * 4096 + s) << 6) + d] = (_Float16)(acc[mb][nb][r] * scale);
        }
  } else {
    // Vp: [b,h][d][s-perm]; within each s-16-block, pos p holds s = (p&3)+8((p>>2)&1)+4(p>>3)
#pragma unroll
    for (int mb = 0; mb < 2; ++mb)
#pragma unroll
      for (int nb = 0; nb < 2; ++nb)
#pragma unroll
        for (int c = 0; c < 4; ++c) {
          const int mbase = m0 + 64 * wm + 32 * mb + 16 * (c >> 1);
          const int n = n0 + 64 * wn + 32 * nb + li;
          const int b = mbase >> 12, sb = mbase & 4095, h = n >> 6, d = n & 63;
          union { uint2 u; _Float16 h4[4]; } t4;
#pragma unroll
          for (int t = 0; t < 4; ++t) t4.h4[t] = (_Float16)acc[mb][nb][4 * c + t];
          *(uint2*)(Vpw + ((((size_t)b * 8 + h) * 64 + d) << 12) + sb + 4 * (c & 1) + 8 * hi) = t4.u;
        }
  }
}

// ---- final projection: att(f16) @ WtO -> out f32
__global__ __launch_bounds__(256) void fgemm_k(const _Float16* __restrict__ A,
                                               const _Float16* __restrict__ Wt,
                                               float* __restrict__ out) {
  __shared__ __align__(16) _Float16 Al[2 * 128 * 64];
  __shared__ __align__(16) _Float16 Bl[2 * 128 * 64];
  const int m0 = blockIdx.x * 128, n0 = blockIdx.y * 128;
  f32x16 acc[2][2];
  gemm_core(A, Wt, m0, n0, Al, Bl, acc);
  const int tid = threadIdx.x, w = tid >> 6, l = tid & 63;
  const int hi = l >> 5, li = l & 31;
  const int wm = w >> 1, wn = w & 1;
#pragma unroll
  for (int mb = 0; mb < 2; ++mb)
#pragma unroll
    for (int nb = 0; nb < 2; ++nb)
#pragma unroll
      for (int r = 0; r < 16; ++r) {
        const int m = m0 + 64 * wm + 32 * mb + (r & 3) + 8 * (r >> 2) + 4 * hi;
        const int n = n0 + 64 * wn + 32 * nb + li;
        out[(size_t)m * 512 + n] = acc[mb][nb][r];
      }
}

// ---- flash v15 (final): split-KV, one barrier period per 128-k pair (32KB sbuf)
__global__ __launch_bounds__(128) void flash_k(const _Float16* __restrict__ Q,
                                               const _Float16* __restrict__ K,
                                               const _Float16* __restrict__ Vp,
                                               _Float16* __restrict__ att,
                                               _Float16* __restrict__ pO,
                                               float2* __restrict__ ml) {
  __shared__ __align__(16) _Float16 Kl[128 * 64];  // [k-row 128][d 64]
  __shared__ __align__(16) _Float16 Vl[64 * 128];  // [d 64][s 128]

  const int u = blockIdx.x;  // 1536 blocks
  const int bh = u & 15;
  const int j = u >> 4;  // 0..95
  int qt, ktlo, kthi, cc;
  if (j < 32) {            // uniform body chunks first (qt>=32, tiles 0..31)
    qt = 32 + j; ktlo = 0; kthi = 31; cc = 0;
  } else {                 // primaries, descending length
    const int i = (j - 32) >> 1;
    qt = ((j - 32) & 1) ? 63 - i : 31 - i;
    ktlo = (qt >= 32) ? 32 : 0;
    kthi = qt; cc = 1;
  }
  const bool split = (qt >= 32);
  const int q0 = qt * 64;
  const int tid = threadIdx.x, w = tid >> 6, l = tid & 63;
  const int hi = l >> 5, li = l & 31;

  const size_t bhoff = (size_t)bh * 4096 * 64;
  const _Float16* Kb = K + bhoff;
  const _Float16* Vb = Vp + bhoff;  // [d][s-perm]
  const _Float16* Qb = Q + bhoff;   // [s][d], pre-scaled by 0.125*log2e
  const int qg = q0 + 32 * w + li;

  f16x8 qB[4];
#pragma unroll
  for (int ks = 0; ks < 4; ++ks)
    qB[ks] = *(const f16x8*)(Qb + (size_t)qg * 64 + 16 * ks + 8 * hi);

  f32x16 o2[2], lacc;
#pragma unroll
  for (int db = 0; db < 2; ++db)
#pragma unroll
    for (int r = 0; r < 16; ++r) o2[db][r] = 0.f;
#pragma unroll
  for (int r = 0; r < 16; ++r) lacc[r] = 0.f;
  float m_ = -__builtin_inff();

  auto tile_step = [&](int kt, int half) {
    f32x16 s2[2];
#pragma unroll
    for (int kb = 0; kb < 2; ++kb)
#pragma unroll
      for (int r = 0; r < 16; ++r) s2[kb][r] = 0.f;
    __builtin_amdgcn_s_setprio(1);
#pragma unroll
    for (int ks = 0; ks < 4; ++ks)
#pragma unroll
      for (int kb = 0; kb < 2; ++kb) {
        const f16x8 kf = *(const f16x8*)(
            (const char*)(Kl + (64 * half + 32 * kb + li) * 64) +
            (((2 * ks + hi) ^ (li & 7)) << 4));
        s2[kb] = mma32(kf, qB[ks], s2[kb]);
      }
    __builtin_amdgcn_s_setprio(0);

    if (kt == qt) {  // diagonal tile mask
      const int limit = 32 * w + li;
#pragma unroll
      for (int kb = 0; kb < 2; ++kb)
#pragma unroll
        for (int r = 0; r < 16; ++r) {
          const int kl = 32 * kb + (r & 3) + 8 * (r >> 2) + 4 * hi;
          if (kl > limit) s2[kb][r] = -__builtin_inff();
        }
    }

#define RV(i) s2[(i) >> 4][(i) & 15]
    float a[11];
#pragma unroll
    for (int i = 0; i < 10; ++i)
      a[i] = fmaxf(fmaxf(RV(3 * i), RV(3 * i + 1)), RV(3 * i + 2));
    a[10] = fmaxf(RV(30), RV(31));
#undef RV
    float b4[4];
    b4[0] = fmaxf(fmaxf(a[0], a[1]), a[2]);
    b4[1] = fmaxf(fmaxf(a[3], a[4]), a[5]);
    b4[2] = fmaxf(fmaxf(a[6], a[7]), a[8]);
    b4[3] = fmaxf(a[9], a[10]);
    const float mxl = fmaxf(fmaxf(fmaxf(b4[0], b4[1]), b4[2]), b4[3]);

    if (!__all(mxl <= m_ + 8.f)) {  // defer-max
      const float vm = fmaxf(mxl, __shfl_xor(mxl, 32, 64));
      const float mn = fmaxf(m_, vm);
      const float al = __builtin_amdgcn_exp2f(m_ - mn);
      m_ = mn;
#pragma unroll
      for (int r = 0; r < 16; ++r) lacc[r] *= al;
#pragma unroll
      for (int db = 0; db < 2; ++db)
#pragma unroll
        for (int r = 0; r < 16; ++r) o2[db][r] *= al;
    }
#pragma unroll
    for (int kb = 0; kb < 2; ++kb)
#pragma unroll
      for (int r = 0; r < 16; ++r) s2[kb][r] = __builtin_amdgcn_exp2f(s2[kb][r] - m_);
#pragma unroll
    for (int kb = 0; kb < 2; ++kb)
#pragma unroll
      for (int r = 0; r < 16; ++r) lacc[r] += s2[kb][r];

    f16x8 pb[4];
#pragma unroll
    for (int ks = 0; ks < 4; ++ks) {
      union { f16x8 v; unsigned int u[4]; } pu;
      const int kb = ks >> 1, base = 8 * (ks & 1);
#pragma unroll
      for (int p2 = 0; p2 < 4; ++p2)
        pu.u[p2] = __builtin_bit_cast(unsigned int,
                     __builtin_amdgcn_cvt_pkrtz(s2[kb][base + 2 * p2], s2[kb][base + 2 * p2 + 1]));
      pb[ks] = pu.v;
    }

    __builtin_amdgcn_s_setprio(1);
#pragma unroll
    for (int ks = 0; ks < 4; ++ks)
#pragma unroll
      for (int db = 0; db < 2; ++db) {
        const f16x8 vf = *(const f16x8*)(
            (const char*)(Vl + (32 * db + li) * 128) +
            ((((8 * half + 2 * ks + hi)) ^ (li & 15)) << 4));
        o2[db] = mma32(vf, pb[ks], o2[db]);
      }
    __builtin_amdgcn_s_setprio(0);
  };

  const int npair = (kthi - ktlo + 2) >> 1;
  for (int p = 0; p < npair; ++p) {
    const int kt0 = ktlo + 2 * p;
    const int k0 = kt0 * 64;
    if (p) __syncthreads();  // all reads of Kl/Vl done before overwrite
#pragma unroll
    for (int e = 0; e < 8; ++e) {
      const int kr = 64 * w + 8 * e;
      gload16(Kb + (size_t)(k0 + kr + (l >> 3)) * 64 + (((l & 7) ^ ((l >> 3) & 7)) << 3),
              Kl + kr * 64);
    }
#pragma unroll
    for (int e = 0; e < 8; ++e) {
      const int vr = 32 * w + 4 * e;
      gload16(Vb + (size_t)(vr + (l >> 4)) * 4096 + k0 +
                  ((((l & 15) ^ ((4 * e + (l >> 4)) & 15))) << 3),
              Vl + vr * 128);
    }
    __syncthreads();  // vmcnt drain + visibility

    tile_step(kt0, 0);
    if (kt0 + 1 <= kthi) tile_step(kt0 + 1, 1);
  }

  // epilogue
  float t8[8];
#pragma unroll
  for (int i = 0; i < 8; ++i) t8[i] = lacc[i] + lacc[i + 8];
  float lsum = ((t8[0] + t8[1]) + (t8[2] + t8[3])) + ((t8[4] + t8[5]) + (t8[6] + t8[7]));
  lsum += __shfl_xor(lsum, 32, 64);
  const float inv = 1.f / lsum;
  if (!split) {
    const int b = bh >> 3, h = bh & 7;
    _Float16* op = att + ((size_t)b * 4096 + qg) * 512 + h * 64;
#pragma unroll
    for (int db = 0; db < 2; ++db)
#pragma unroll
      for (int c = 0; c < 4; ++c) {
        union { uint2 u; _Float16 h4[4]; } t4;
#pragma unroll
        for (int t = 0; t < 4; ++t) t4.h4[t] = (_Float16)(o2[db][4 * c + t] * inv);
        *(uint2*)(op + 32 * db + 8 * c + 4 * hi) = t4.u;
      }
  } else {
    const int slot = (bh * 32 + (qt - 32)) * 2 + cc;
    const int qrow = 32 * w + li;
    _Float16* op = pO + (size_t)slot * 4096 + qrow * 64;
#pragma unroll
    for (int db = 0; db < 2; ++db)
#pragma unroll
      for (int c = 0; c < 4; ++c) {
        union { uint2 u; _Float16 h4[4]; } t4;
#pragma unroll
        for (int t = 0; t < 4; ++t) t4.h4[t] = (_Float16)(o2[db][4 * c + t] * inv);
        *(uint2*)(op + 32 * db + 8 * c + 4 * hi) = t4.u;
      }
    if (hi == 0) ml[slot * 64 + qrow] = make_float2(m_, lsum);
  }
}

// ---- combine: merge 2 normalized partials per (bh, qt>=32, qrow) -> att
__global__ __launch_bounds__(256) void combine_k(const float2* __restrict__ ml,
                                                 const _Float16* __restrict__ pO,
                                                 _Float16* __restrict__ att) {
  const int tid = threadIdx.x;
  const int rid = blockIdx.x * 8 + (tid >> 5);  // 32768 rows total
  const int d2 = tid & 31;
  const int bh = rid >> 11, rem = rid & 2047;
  const int qm = rem >> 6, qrow = rem & 63;
  const int slot0 = (bh * 32 + qm) * 2;
  const float2 ml0 = ml[slot0 * 64 + qrow];
  const float2 ml1 = ml[slot0 * 64 + 64 + qrow];
  const float M = fmaxf(ml0.x, ml1.x);
  const float w0 = __builtin_amdgcn_exp2f(ml0.x - M) * ml0.y;
  const float w1 = __builtin_amdgcn_exp2f(ml1.x - M) * ml1.y;
  const float inv = 1.f / (w0 + w1);
  const float a0 = w0 * inv, a1 = w1 * inv;
  union { unsigned int u; _Float16 h2[2]; } x0, x1, y;
  x0.u = *(const unsigned int*)(pO + (size_t)slot0 * 4096 + qrow * 64 + 2 * d2);
  x1.u = *(const unsigned int*)(pO + (size_t)(slot0 + 1) * 4096 + qrow * 64 + 2 * d2);
  y.h2[0] = (_Float16)((float)x0.h2[0] * a0 + (float)x1.h2[0] * a1);
  y.h2[1] = (_Float16)((float)x0.h2[1] * a0 + (float)x1.h2[1] * a1);
  const int b = bh >> 3, h = bh & 7, q = (32 + qm) * 64 + qrow;
  *(unsigned int*)(att + ((size_t)b * 4096 + q) * 512 + h * 64 + 2 * d2) = y.u;
}

extern "C" void kernel_launch(void* const* d_in, const int* in_sizes, int n_in,
                              void* d_out, int out_size, void* d_ws, size_t ws_size,
                              hipStream_t stream) {
  const float* enc = (const float*)d_in[0];
  const float* WQ = (const float*)d_in[2];
  const float* WK = (const float*)d_in[3];
  const float* WV = (const float*)d_in[4];
  const float* WO = (const float*)d_in[5];
  float* out = (float*)d_out;

  const size_t NE = (size_t)2 * 8 * 4096 * 64;  // 4,194,304
  _Float16* enc16 = (_Float16*)d_ws;            // 8MB; aliased with partial-O (enc16 dead after qkv)
  _Float16* pO = enc16;
  _Float16* Qw = enc16 + NE;
  _Float16* Kw = Qw + NE;
  _Float16* Vpw = Kw + NE;
  _Float16* WtQ = Vpw + NE;                     // 0.5MB; aliased with ml (WtQ dead after qkv)
  _Float16* WtK = WtQ + 512 * 512;
  _Float16* WtV = WtK + 512 * 512;
  _Float16* WtO = WtV + 512 * 512;
  _Float16* att = WtO + 512 * 512;              // 8MB
  float2* ml = (float2*)WtQ;                    // 512KB

  prep_k<<<3072, 256, 0, stream>>>(enc, WQ, WK, WV, WO, enc16, WtQ, WtK, WtV, WtO);
  // 0.125 (1/sqrt(64)) * log2(e) folded into Q
  qkv_k<<<dim3(64, 12), 256, 0, stream>>>(enc16, WtQ, WtK, WtV, Qw, Kw, Vpw, 0.1803368801f);
  flash_k<<<1536, 128, 0, stream>>>(Qw, Kw, Vpw, att, pO, ml);
  combine_k<<<4096, 256, 0, stream>>>(ml, pO, att);
  fgemm_k<<<dim3(64, 4), 256, 0, stream>>>(att, WtO, out);
}

// Round 19
// 105.532 us; speedup vs baseline: 1.3908x; 1.0546x over previous
//
#include <hip/hip_runtime.h>

// B=2, S=4096, D=512, H=8, DH=64
// ws (f16): [enc16 | partialO] 8MB | Q 8MB | K 8MB | Vp 8MB | [WtQ|ml 0.5MB] WtK WtV WtO | att 8MB
// All MFMA: 32x32x16 f16. C/D map (m74/m101): col=l&31, row=(r&3)+8*(r>>2)+4*(l>>5).

typedef _Float16 f16x8 __attribute__((ext_vector_type(8)));
typedef float f32x16 __attribute__((ext_vector_type(16)));

__device__ __forceinline__ f32x16 mma32(f16x8 a, f16x8 b, f32x16 c) {
  return __builtin_amdgcn_mfma_f32_32x32x16_f16(a, b, c, 0, 0, 0);
}

__device__ __forceinline__ void gload16(const void* g, void* l) {
  __builtin_amdgcn_global_load_lds((const __attribute__((address_space(1))) void*)g,
                                   (__attribute__((address_space(3))) void*)l, 16, 0, 0);
}

// ---- prep: enc f32->f16 (blocks 0..2047) + 4x W transpose->f16 (blocks 2048..3071)
__global__ __launch_bounds__(256) void prep_k(const float* __restrict__ enc,
                                              const float* __restrict__ WQ,
                                              const float* __restrict__ WK,
                                              const float* __restrict__ WV,
                                              const float* __restrict__ WO,
                                              _Float16* __restrict__ enc16,
                                              _Float16* __restrict__ WtQ,
                                              _Float16* __restrict__ WtK,
                                              _Float16* __restrict__ WtV,
                                              _Float16* __restrict__ WtO) {
  const int bid = blockIdx.x;
  if (bid < 2048) {
    const size_t i = (size_t)bid * 256 + threadIdx.x;  // 8 elems each
    const float4* p = (const float4*)(enc + i * 8);
    const float4 a = p[0], b = p[1];
    union { f16x8 v; uint4 u; } r;
    r.v[0] = (_Float16)a.x; r.v[1] = (_Float16)a.y; r.v[2] = (_Float16)a.z; r.v[3] = (_Float16)a.w;
    r.v[4] = (_Float16)b.x; r.v[5] = (_Float16)b.y; r.v[6] = (_Float16)b.z; r.v[7] = (_Float16)b.w;
    *(uint4*)(enc16 + i * 8) = r.u;
  } else {
    const int t = bid - 2048;
    const int wsel = t >> 8;
    const float* W = (wsel == 0) ? WQ : (wsel == 1) ? WK : (wsel == 2) ? WV : WO;
    _Float16* T = (wsel == 0) ? WtQ : (wsel == 1) ? WtK : (wsel == 2) ? WtV : WtO;
    const int tb = t & 255;
    const int k0 = (tb & 15) * 32, n0 = (tb >> 4) * 32;
    __shared__ float tt[32][33];
    const int c = threadIdx.x & 31, r8 = threadIdx.x >> 5;
#pragma unroll
    for (int p = 0; p < 4; ++p) tt[c][r8 + 8 * p] = W[(size_t)(k0 + r8 + 8 * p) * 512 + n0 + c];
    __syncthreads();
#pragma unroll
    for (int p = 0; p < 4; ++p)
      T[(size_t)(n0 + r8 + 8 * p) * 512 + k0 + c] = (_Float16)tt[r8 + 8 * p][c];
  }
}

// ---- shared GEMM core: C128x128, BK=64, 4 waves (2x2), SINGLE-buffer LDS (32KB
// -> 4 blocks/CU; m97 structure: TLP hides the stage latency, not intra-block dbuf)
__device__ __forceinline__ void gemm_core(const _Float16* __restrict__ A,
                                          const _Float16* __restrict__ Wt,
                                          int m0, int n0,
                                          _Float16* Al, _Float16* Bl,
                                          f32x16 acc[2][2]) {
  const int tid = threadIdx.x, w = tid >> 6, l = tid & 63;
  const int hi = l >> 5, li = l & 31;
  const int wm = w >> 1, wn = w & 1;
  const int srow = l >> 3, sunit = (l & 7) ^ (l >> 3);
  const int arow = 32 * w;

#pragma unroll
  for (int mb = 0; mb < 2; ++mb)
#pragma unroll
    for (int nb = 0; nb < 2; ++nb)
#pragma unroll
      for (int r = 0; r < 16; ++r) acc[mb][nb][r] = 0.f;

  for (int kk = 0; kk < 8; ++kk) {
    const int kn = kk * 64;
    if (kk) __syncthreads();  // all reads of the buffer done
#pragma unroll
    for (int i = 0; i < 4; ++i) {
      gload16(A + (size_t)(m0 + arow + 8 * i + srow) * 512 + kn + sunit * 8,
              Al + (arow + 8 * i) * 64);
      gload16(Wt + (size_t)(n0 + arow + 8 * i + srow) * 512 + kn + sunit * 8,
              Bl + (arow + 8 * i) * 64);
    }
    __syncthreads();  // vmcnt drain + visibility
#pragma unroll
    for (int ks = 0; ks < 4; ++ks) {
      f16x8 af[2], bf[2];
#pragma unroll
      for (int mb = 0; mb < 2; ++mb)
        af[mb] = *(const f16x8*)((const char*)(Al + (64 * wm + 32 * mb + li) * 64) +
                                 (((2 * ks + hi) ^ (li & 7)) << 4));
#pragma unroll
      for (int nb = 0; nb < 2; ++nb)
        bf[nb] = *(const f16x8*)((const char*)(Bl + (64 * wn + 32 * nb + li) * 64) +
                                 (((2 * ks + hi) ^ (li & 7)) << 4));
#pragma unroll
      for (int mb = 0; mb < 2; ++mb)
#pragma unroll
        for (int nb = 0; nb < 2; ++nb) acc[mb][nb] = mma32(af[mb], bf[nb], acc[mb][nb]);
    }
  }
}

// ---- fused QKV projection: grid (64, 12); y>>2 selects W; y&3 selects n0
__global__ __launch_bounds__(256) void qkv_k(const _Float16* __restrict__ A,
                                             const _Float16* __restrict__ WtQ,
                                             const _Float16* __restrict__ WtK,
                                             const _Float16* __restrict__ WtV,
                                             _Float16* __restrict__ Qw,
                                             _Float16* __restrict__ Kw,
                                             _Float16* __restrict__ Vpw,
                                             float qscale) {
  __shared__ __align__(16) _Float16 Al[128 * 64];
  __shared__ __align__(16) _Float16 Bl[128 * 64];
  const int m0 = blockIdx.x * 128;
  const int wid = blockIdx.y >> 2, n0 = (blockIdx.y & 3) * 128;
  const _Float16* Wt = (wid == 0) ? WtQ : (wid == 1) ? WtK : WtV;
  f32x16 acc[2][2];
  gemm_core(A, Wt, m0, n0, Al, Bl, acc);

  const int tid = threadIdx.x, w = tid >> 6, l = tid & 63;
  const int hi = l >> 5, li = l & 31;
  const int wm = w >> 1, wn = w & 1;
  if (wid < 2) {
    _Float16* Cp = (wid == 0) ? Qw : Kw;
    const float scale = (wid == 0) ? qscale : 1.f;
#pragma unroll
    for (int mb = 0; mb < 2; ++mb)
#pragma unroll
      for (int nb = 0; nb < 2; ++nb)
#pragma unroll
        for (int r = 0; r < 16; ++r) {
          const int m = m0 + 64 * wm + 32 * mb + (r & 3) + 8 * (r >> 2) + 4 * hi;
          const int n = n0 + 64 * wn + 32 * nb + li;
          const int b = m >> 12, s = m & 4095, h = n >> 6, d = n & 63;
          Cp[((((size_t)b * 8 + h) * 4096 + s) << 6) + d] = (_Float16)(acc[mb][nb][r] * scale);
        }
  } else {
    // Vp: [b,h][d][s-perm]; within each s-16-block, pos p holds s = (p&3)+8((p>>2)&1)+4(p>>3)
#pragma unroll
    for (int mb = 0; mb < 2; ++mb)
#pragma unroll
      for (int nb = 0; nb < 2; ++nb)
#pragma unroll
        for (int c = 0; c < 4; ++c) {
          const int mbase = m0 + 64 * wm + 32 * mb + 16 * (c >> 1);
          const int n = n0 + 64 * wn + 32 * nb + li;
          const int b = mbase >> 12, sb = mbase & 4095, h = n >> 6, d = n & 63;
          union { uint2 u; _Float16 h4[4]; } t4;
#pragma unroll
          for (int t = 0; t < 4; ++t) t4.h4[t] = (_Float16)acc[mb][nb][4 * c + t];
          *(uint2*)(Vpw + ((((size_t)b * 8 + h) * 64 + d) << 12) + sb + 4 * (c & 1) + 8 * hi) = t4.u;
        }
  }
}

// ---- final projection: att(f16) @ WtO -> out f32
__global__ __launch_bounds__(256) void fgemm_k(const _Float16* __restrict__ A,
                                               const _Float16* __restrict__ Wt,
                                               float* __restrict__ out) {
  __shared__ __align__(16) _Float16 Al[128 * 64];
  __shared__ __align__(16) _Float16 Bl[128 * 64];
  const int m0 = blockIdx.x * 128, n0 = blockIdx.y * 128;
  f32x16 acc[2][2];
  gemm_core(A, Wt, m0, n0, Al, Bl, acc);
  const int tid = threadIdx.x, w = tid >> 6, l = tid & 63;
  const int hi = l >> 5, li = l & 31;
  const int wm = w >> 1, wn = w & 1;
#pragma unroll
  for (int mb = 0; mb < 2; ++mb)
#pragma unroll
    for (int nb = 0; nb < 2; ++nb)
#pragma unroll
      for (int r = 0; r < 16; ++r) {
        const int m = m0 + 64 * wm + 32 * mb + (r & 3) + 8 * (r >> 2) + 4 * hi;
        const int n = n0 + 64 * wn + 32 * nb + li;
        out[(size_t)m * 512 + n] = acc[mb][nb][r];
      }
}

// ---- flash v15 (final): split-KV, one barrier period per 128-k pair (32KB sbuf)
__global__ __launch_bounds__(128) void flash_k(const _Float16* __restrict__ Q,
                                               const _Float16* __restrict__ K,
                                               const _Float16* __restrict__ Vp,
                                               _Float16* __restrict__ att,
                                               _Float16* __restrict__ pO,
                                               float2* __restrict__ ml) {
  __shared__ __align__(16) _Float16 Kl[128 * 64];  // [k-row 128][d 64]
  __shared__ __align__(16) _Float16 Vl[64 * 128];  // [d 64][s 128]

  const int u = blockIdx.x;  // 1536 blocks
  const int bh = u & 15;
  const int j = u >> 4;  // 0..95
  int qt, ktlo, kthi, cc;
  if (j < 32) {            // uniform body chunks first (qt>=32, tiles 0..31)
    qt = 32 + j; ktlo = 0; kthi = 31; cc = 0;
  } else {                 // primaries, descending length
    const int i = (j - 32) >> 1;
    qt = ((j - 32) & 1) ? 63 - i : 31 - i;
    ktlo = (qt >= 32) ? 32 : 0;
    kthi = qt; cc = 1;
  }
  const bool split = (qt >= 32);
  const int q0 = qt * 64;
  const int tid = threadIdx.x, w = tid >> 6, l = tid & 63;
  const int hi = l >> 5, li = l & 31;

  const size_t bhoff = (size_t)bh * 4096 * 64;
  const _Float16* Kb = K + bhoff;
  const _Float16* Vb = Vp + bhoff;  // [d][s-perm]
  const _Float16* Qb = Q + bhoff;   // [s][d], pre-scaled by 0.125*log2e
  const int qg = q0 + 32 * w + li;

  f16x8 qB[4];
#pragma unroll
  for (int ks = 0; ks < 4; ++ks)
    qB[ks] = *(const f16x8*)(Qb + (size_t)qg * 64 + 16 * ks + 8 * hi);

  f32x16 o2[2], lacc;
#pragma unroll
  for (int db = 0; db < 2; ++db)
#pragma unroll
    for (int r = 0; r < 16; ++r) o2[db][r] = 0.f;
#pragma unroll
  for (int r = 0; r < 16; ++r) lacc[r] = 0.f;
  float m_ = -__builtin_inff();

  auto tile_step = [&](int kt, int half) {
    f32x16 s2[2];
#pragma unroll
    for (int kb = 0; kb < 2; ++kb)
#pragma unroll
      for (int r = 0; r < 16; ++r) s2[kb][r] = 0.f;
    __builtin_amdgcn_s_setprio(1);
#pragma unroll
    for (int ks = 0; ks < 4; ++ks)
#pragma unroll
      for (int kb = 0; kb < 2; ++kb) {
        const f16x8 kf = *(const f16x8*)(
            (const char*)(Kl + (64 * half + 32 * kb + li) * 64) +
            (((2 * ks + hi) ^ (li & 7)) << 4));
        s2[kb] = mma32(kf, qB[ks], s2[kb]);
      }
    __builtin_amdgcn_s_setprio(0);

    if (kt == qt) {  // diagonal tile mask
      const int limit = 32 * w + li;
#pragma unroll
      for (int kb = 0; kb < 2; ++kb)
#pragma unroll
        for (int r = 0; r < 16; ++r) {
          const int kl = 32 * kb + (r & 3) + 8 * (r >> 2) + 4 * hi;
          if (kl > limit) s2[kb][r] = -__builtin_inff();
        }
    }

#define RV(i) s2[(i) >> 4][(i) & 15]
    float a[11];
#pragma unroll
    for (int i = 0; i < 10; ++i)
      a[i] = fmaxf(fmaxf(RV(3 * i), RV(3 * i + 1)), RV(3 * i + 2));
    a[10] = fmaxf(RV(30), RV(31));
#undef RV
    float b4[4];
    b4[0] = fmaxf(fmaxf(a[0], a[1]), a[2]);
    b4[1] = fmaxf(fmaxf(a[3], a[4]), a[5]);
    b4[2] = fmaxf(fmaxf(a[6], a[7]), a[8]);
    b4[3] = fmaxf(a[9], a[10]);
    const float mxl = fmaxf(fmaxf(fmaxf(b4[0], b4[1]), b4[2]), b4[3]);

    if (!__all(mxl <= m_ + 8.f)) {  // defer-max
      const float vm = fmaxf(mxl, __shfl_xor(mxl, 32, 64));
      const float mn = fmaxf(m_, vm);
      const float al = __builtin_amdgcn_exp2f(m_ - mn);
      m_ = mn;
#pragma unroll
      for (int r = 0; r < 16; ++r) lacc[r] *= al;
#pragma unroll
      for (int db = 0; db < 2; ++db)
#pragma unroll
        for (int r = 0; r < 16; ++r) o2[db][r] *= al;
    }
#pragma unroll
    for (int kb = 0; kb < 2; ++kb)
#pragma unroll
      for (int r = 0; r < 16; ++r) s2[kb][r] = __builtin_amdgcn_exp2f(s2[kb][r] - m_);
#pragma unroll
    for (int kb = 0; kb < 2; ++kb)
#pragma unroll
      for (int r = 0; r < 16; ++r) lacc[r] += s2[kb][r];

    f16x8 pb[4];
#pragma unroll
    for (int ks = 0; ks < 4; ++ks) {
      union { f16x8 v; unsigned int u[4]; } pu;
      const int kb = ks >> 1, base = 8 * (ks & 1);
#pragma unroll
      for (int p2 = 0; p2 < 4; ++p2)
        pu.u[p2] = __builtin_bit_cast(unsigned int,
                     __builtin_amdgcn_cvt_pkrtz(s2[kb][base + 2 * p2], s2[kb][base + 2 * p2 + 1]));
      pb[ks] = pu.v;
    }

    __builtin_amdgcn_s_setprio(1);
#pragma unroll
    for (int ks = 0; ks < 4; ++ks)
#pragma unroll
      for (int db = 0; db < 2; ++db) {
        const f16x8 vf = *(const f16x8*)(
            (const char*)(Vl + (32 * db + li) * 128) +
            ((((8 * half + 2 * ks + hi)) ^ (li & 15)) << 4));
        o2[db] = mma32(vf, pb[ks], o2[db]);
      }
    __builtin_amdgcn_s_setprio(0);
  };

  const int npair = (kthi - ktlo + 2) >> 1;
  for (int p = 0; p < npair; ++p) {
    const int kt0 = ktlo + 2 * p;
    const int k0 = kt0 * 64;
    if (p) __syncthreads();  // all reads of Kl/Vl done before overwrite
#pragma unroll
    for (int e = 0; e < 8; ++e) {
      const int kr = 64 * w + 8 * e;
      gload16(Kb + (size_t)(k0 + kr + (l >> 3)) * 64 + (((l & 7) ^ ((l >> 3) & 7)) << 3),
              Kl + kr * 64);
    }
#pragma unroll
    for (int e = 0; e < 8; ++e) {
      const int vr = 32 * w + 4 * e;
      gload16(Vb + (size_t)(vr + (l >> 4)) * 4096 + k0 +
                  ((((l & 15) ^ ((4 * e + (l >> 4)) & 15))) << 3),
              Vl + vr * 128);
    }
    __syncthreads();  // vmcnt drain + visibility

    tile_step(kt0, 0);
    if (kt0 + 1 <= kthi) tile_step(kt0 + 1, 1);
  }

  // epilogue
  float t8[8];
#pragma unroll
  for (int i = 0; i < 8; ++i) t8[i] = lacc[i] + lacc[i + 8];
  float lsum = ((t8[0] + t8[1]) + (t8[2] + t8[3])) + ((t8[4] + t8[5]) + (t8[6] + t8[7]));
  lsum += __shfl_xor(lsum, 32, 64);
  const float inv = 1.f / lsum;
  if (!split) {
    const int b = bh >> 3, h = bh & 7;
    _Float16* op = att + ((size_t)b * 4096 + qg) * 512 + h * 64;
#pragma unroll
    for (int db = 0; db < 2; ++db)
#pragma unroll
      for (int c = 0; c < 4; ++c) {
        union { uint2 u; _Float16 h4[4]; } t4;
#pragma unroll
        for (int t = 0; t < 4; ++t) t4.h4[t] = (_Float16)(o2[db][4 * c + t] * inv);
        *(uint2*)(op + 32 * db + 8 * c + 4 * hi) = t4.u;
      }
  } else {
    const int slot = (bh * 32 + (qt - 32)) * 2 + cc;
    const int qrow = 32 * w + li;
    _Float16* op = pO + (size_t)slot * 4096 + qrow * 64;
#pragma unroll
    for (int db = 0; db < 2; ++db)
#pragma unroll
      for (int c = 0; c < 4; ++c) {
        union { uint2 u; _Float16 h4[4]; } t4;
#pragma unroll
        for (int t = 0; t < 4; ++t) t4.h4[t] = (_Float16)(o2[db][4 * c + t] * inv);
        *(uint2*)(op + 32 * db + 8 * c + 4 * hi) = t4.u;
      }
    if (hi == 0) ml[slot * 64 + qrow] = make_float2(m_, lsum);
  }
}

// ---- combine: merge 2 normalized partials per (bh, qt>=32, qrow) -> att
__global__ __launch_bounds__(256) void combine_k(const float2* __restrict__ ml,
                                                 const _Float16* __restrict__ pO,
                                                 _Float16* __restrict__ att) {
  const int tid = threadIdx.x;
  const int rid = blockIdx.x * 8 + (tid >> 5);  // 32768 rows total
  const int d2 = tid & 31;
  const int bh = rid >> 11, rem = rid & 2047;
  const int qm = rem >> 6, qrow = rem & 63;
  const int slot0 = (bh * 32 + qm) * 2;
  const float2 ml0 = ml[slot0 * 64 + qrow];
  const float2 ml1 = ml[slot0 * 64 + 64 + qrow];
  const float M = fmaxf(ml0.x, ml1.x);
  const float w0 = __builtin_amdgcn_exp2f(ml0.x - M) * ml0.y;
  const float w1 = __builtin_amdgcn_exp2f(ml1.x - M) * ml1.y;
  const float inv = 1.f / (w0 + w1);
  const float a0 = w0 * inv, a1 = w1 * inv;
  union { unsigned int u; _Float16 h2[2]; } x0, x1, y;
  x0.u = *(const unsigned int*)(pO + (size_t)slot0 * 4096 + qrow * 64 + 2 * d2);
  x1.u = *(const unsigned int*)(pO + (size_t)(slot0 + 1) * 4096 + qrow * 64 + 2 * d2);
  y.h2[0] = (_Float16)((float)x0.h2[0] * a0 + (float)x1.h2[0] * a1);
  y.h2[1] = (_Float16)((float)x0.h2[1] * a0 + (float)x1.h2[1] * a1);
  const int b = bh >> 3, h = bh & 7, q = (32 + qm) * 64 + qrow;
  *(unsigned int*)(att + ((size_t)b * 4096 + q) * 512 + h * 64 + 2 * d2) = y.u;
}

extern "C" void kernel_launch(void* const* d_in, const int* in_sizes, int n_in,
                              void* d_out, int out_size, void* d_ws, size_t ws_size,
                              hipStream_t stream) {
  const float* enc = (const float*)d_in[0];
  const float* WQ = (const float*)d_in[2];
  const float* WK = (const float*)d_in[3];
  const float* WV = (const float*)d_in[4];
  const float* WO = (const float*)d_in[5];
  float* out = (float*)d_out;

  const size_t NE = (size_t)2 * 8 * 4096 * 64;  // 4,194,304
  _Float16* enc16 = (_Float16*)d_ws;            // 8MB; aliased with partial-O (enc16 dead after qkv)
  _Float16* pO = enc16;
  _Float16* Qw = enc16 + NE;
  _Float16* Kw = Qw + NE;
  _Float16* Vpw = Kw + NE;
  _Float16* WtQ = Vpw + NE;                     // 0.5MB; aliased with ml (WtQ dead after qkv)
  _Float16* WtK = WtQ + 512 * 512;
  _Float16* WtV = WtK + 512 * 512;
  _Float16* WtO = WtV + 512 * 512;
  _Float16* att = WtO + 512 * 512;              // 8MB
  float2* ml = (float2*)WtQ;                    // 512KB

  prep_k<<<3072, 256, 0, stream>>>(enc, WQ, WK, WV, WO, enc16, WtQ, WtK, WtV, WtO);
  // 0.125 (1/sqrt(64)) * log2(e) folded into Q
  qkv_k<<<dim3(64, 12), 256, 0, stream>>>(enc16, WtQ, WtK, WtV, Qw, Kw, Vpw, 0.1803368801f);
  flash_k<<<1536, 128, 0, stream>>>(Qw, Kw, Vpw, att, pO, ml);
  combine_k<<<4096, 256, 0, stream>>>(ml, pO, att);
  fgemm_k<<<dim3(64, 4), 256, 0, stream>>>(att, WtO, out);
}